// Round 6
// baseline (580.433 us; speedup 1.0000x reference)
//
#include <hip/hip_runtime.h>
#include <cstdint>

#define Nn 50000
#define Dd 64
#define Ee 800000
#define NBLK 196          // ceil(Nn/256)
#define ND4 (Nn*Dd/4)     // 800000 float4s
#define NDTOT ((size_t)Nn * 64)

__device__ __forceinline__ float relu_f(float v){ return v > 0.f ? v : 0.f; }

// bf16 <-> fp32 (RNE round)
__device__ __forceinline__ unsigned short f2bf(float f){
    unsigned u = __float_as_uint(f);
    u += 0x7fffu + ((u >> 16) & 1u);
    return (unsigned short)(u >> 16);
}
// accumulate 8 packed bf16 (uint4) into fp32[8]
__device__ __forceinline__ void add_bf8(float* a, uint4 u){
    a[0] += __uint_as_float(u.x << 16);
    a[1] += __uint_as_float(u.x & 0xffff0000u);
    a[2] += __uint_as_float(u.y << 16);
    a[3] += __uint_as_float(u.y & 0xffff0000u);
    a[4] += __uint_as_float(u.z << 16);
    a[5] += __uint_as_float(u.z & 0xffff0000u);
    a[6] += __uint_as_float(u.w << 16);
    a[7] += __uint_as_float(u.w & 0xffff0000u);
}

// ---- degree histogram (self-loops added later as +1) ----
__global__ __launch_bounds__(256) void k_degree(const int* __restrict__ src, const int* __restrict__ dst,
                                                unsigned* __restrict__ dout, unsigned* __restrict__ din){
    int e = blockIdx.x * 256 + threadIdx.x;
    if (e < Ee){
        atomicAdd(&dout[src[e]], 1u);
        atomicAdd(&din[dst[e]], 1u);
    }
}

// ---- block sums of deg_in (for scan) + norms fused ----
__global__ __launch_bounds__(256) void k_blocksum(const unsigned* __restrict__ din, const unsigned* __restrict__ dout,
                                                  unsigned* __restrict__ bsum,
                                                  float* __restrict__ ns, float* __restrict__ nd){
    __shared__ unsigned s[256];
    int t = threadIdx.x; int i = blockIdx.x * 256 + t;
    unsigned v = (i < Nn) ? din[i] : 0u;
    s[t] = v;
    if (i < Nn){
        ns[i] = rsqrtf((float)(dout[i] + 1u));   // +1 = self loop
        nd[i] = rsqrtf((float)(v + 1u));
    }
    __syncthreads();
    for (int off = 128; off > 0; off >>= 1){ if (t < off) s[t] += s[t + off]; __syncthreads(); }
    if (t == 0) bsum[blockIdx.x] = s[0];
}

__global__ __launch_bounds__(256) void k_scanblocks(const unsigned* __restrict__ bsum, unsigned* __restrict__ boff,
                                                    unsigned* __restrict__ offsets){
    __shared__ unsigned s[256];
    int t = threadIdx.x;
    unsigned v = (t < NBLK) ? bsum[t] : 0u;
    s[t] = v; __syncthreads();
    for (int off = 1; off < 256; off <<= 1){
        unsigned add = (t >= off) ? s[t - off] : 0u;
        __syncthreads();
        s[t] += add;
        __syncthreads();
    }
    boff[t] = s[t] - v;                       // exclusive prefix of block sums
    if (t == 255) offsets[Nn] = s[255];       // total == Ee
}

__global__ __launch_bounds__(256) void k_offsets(const unsigned* __restrict__ din, const unsigned* __restrict__ boff,
                                                 unsigned* __restrict__ offsets, unsigned* __restrict__ cursor){
    __shared__ unsigned s[256];
    int t = threadIdx.x; int i = blockIdx.x * 256 + t;
    unsigned v = (i < Nn) ? din[i] : 0u;
    s[t] = v; __syncthreads();
    for (int off = 1; off < 256; off <<= 1){
        unsigned add = (t >= off) ? s[t - off] : 0u;
        __syncthreads();
        s[t] += add;
        __syncthreads();
    }
    if (i < Nn){
        unsigned val = s[t] - v + boff[blockIdx.x];
        offsets[i] = val;
        cursor[i]  = val;
    }
}

__global__ __launch_bounds__(256) void k_fillcsr(const int* __restrict__ src, const int* __restrict__ dst,
                                                 unsigned* __restrict__ cursor, unsigned* __restrict__ csr){
    int e = blockIdx.x * 256 + threadIdx.x;
    if (e < Ee){
        unsigned pos = atomicAdd(&cursor[dst[e]], 1u);
        csr[pos] = (unsigned)src[e];
    }
}

// ---- h0 = bf16(F * norm_src) — layer-0 input only ----
__global__ __launch_bounds__(256) void k_h0(const float* __restrict__ x, const float* __restrict__ ns,
                                            unsigned short* __restrict__ h){
    int i = blockIdx.x * 256 + threadIdx.x;   // exactly ND4 threads
    const float4* x4 = (const float4*)x;
    float s = ns[i >> 4];
    float4 v = x4[i];
    ushort4 o;
    o.x = f2bf(v.x * s); o.y = f2bf(v.y * s);
    o.z = f2bf(v.z * s); o.w = f2bf(v.w * s);
    ((ushort4*)h)[i] = o;
}

// Per-wave fused body: gather one node's rows (8 edge slots x unroll 2 = 16
// rows in flight), butterfly over slots, scale by nd, then per-lane GEMM row:
// y[lane] = b[lane] + sum_k agg[k] * Ws[k*64+lane]. agg broadcast via __shfl
// (uniform lane -> v_readlane), Ws reads are 2-way bank aliased (free).
// Returns y (pre-relu). Requires Ws staged + __syncthreads done by caller.
__device__ __forceinline__ float layer_body(const unsigned short* __restrict__ h,
                                            const unsigned* __restrict__ offsets,
                                            const unsigned* __restrict__ csr,
                                            const float* __restrict__ nd,
                                            const float* __restrict__ bias,
                                            const float* Ws, int v, int lane){
    int slot = lane >> 3;          // 0..7 edge slot
    int sub  = lane & 7;           // 0..7 chunk: elems sub*8 .. sub*8+7
    const uint4* h16 = (const uint4*)h;   // 8 uint4 per 128B row

    float acc[8];
    #pragma unroll
    for (int i = 0; i < 8; i++) acc[i] = 0.f;

    unsigned beg = offsets[v], end = offsets[v + 1];

    if (slot == 0){                // self loop: 8 lanes cover the 128B row
        add_bf8(acc, h16[(size_t)v * 8 + sub]);
    }

    unsigned e = beg + slot;
    for (; e + 8 < end; e += 16){
        int s0 = (int)csr[e];
        int s1 = (int)csr[e + 8];
        uint4 u0 = h16[(size_t)s0 * 8 + sub];
        uint4 u1 = h16[(size_t)s1 * 8 + sub];
        add_bf8(acc, u0);
        add_bf8(acc, u1);
    }
    if (e < end){
        add_bf8(acc, h16[(size_t)((int)csr[e]) * 8 + sub]);
    }

    // reduce over slots (lane bits 3..5): after this every lane holds the
    // full sums for chunk (lane&7): acc[i] == agg[(lane&7)*8 + i]
    #pragma unroll
    for (int i = 0; i < 8; i++) acc[i] += __shfl_xor(acc[i], 8, 64);
    #pragma unroll
    for (int i = 0; i < 8; i++) acc[i] += __shfl_xor(acc[i], 16, 64);
    #pragma unroll
    for (int i = 0; i < 8; i++) acc[i] += __shfl_xor(acc[i], 32, 64);

    float ndv = nd[v];
    #pragma unroll
    for (int i = 0; i < 8; i++) acc[i] *= ndv;

    // per-lane GEMM row: agg[8c+i] lives in acc[i] of lane c (c<8)
    float y = bias[lane];
    #pragma unroll
    for (int c = 0; c < 8; c++){
        #pragma unroll
        for (int i = 0; i < 8; i++){
            float a = __shfl(acc[i], c, 64);       // uniform-lane broadcast
            y = fmaf(a, Ws[(c * 8 + i) * 64 + lane], y);
        }
    }
    return y;
}

// ---- layers 0,1: fused gather+GEMM, out = bf16(relu(y)*ns) ----
__global__ __launch_bounds__(256) void k_layer01(const unsigned short* __restrict__ hin,
                                                 const unsigned* __restrict__ offsets,
                                                 const unsigned* __restrict__ csr,
                                                 const float* __restrict__ nd, const float* __restrict__ ns,
                                                 const float* __restrict__ W, const float* __restrict__ bias,
                                                 unsigned short* __restrict__ hout){
    __shared__ float Ws[4096];     // 16 KB: W[k][n]
    int t = threadIdx.x;
    {   // stage W
        const float4* W4 = (const float4*)W;
        float4* Ws4 = (float4*)Ws;
        #pragma unroll
        for (int i = 0; i < 4; i++) Ws4[t + 256 * i] = W4[t + 256 * i];
    }
    __syncthreads();
    int v = blockIdx.x * 4 + (t >> 6);   // 12500 blocks * 4 waves = 50000 nodes
    int lane = t & 63;
    float y = layer_body(hin, offsets, csr, nd, bias, Ws, v, lane);
    y = relu_f(y);
    hout[(size_t)v * 64 + lane] = f2bf(y * ns[v]);   // prescale for next layer
}

// ---- layer 2 + fc fused: y=relu(...), then p[o] = y * fc_w[o][v*64+lane];
// LDS-transpose reduce (reusing Ws post-barrier) -> per-block partials[16]. ----
__global__ __launch_bounds__(256) void k_layer2fc(const unsigned short* __restrict__ hin,
                                                  const unsigned* __restrict__ offsets,
                                                  const unsigned* __restrict__ csr,
                                                  const float* __restrict__ nd,
                                                  const float* __restrict__ W, const float* __restrict__ bias,
                                                  const float* __restrict__ fcw,
                                                  float* __restrict__ partials){
    __shared__ float Ws[4096];     // 16 KB: W[k][n], reused as p-transpose after barrier
    int t = threadIdx.x;
    {
        const float4* W4 = (const float4*)W;
        float4* Ws4 = (float4*)Ws;
        #pragma unroll
        for (int i = 0; i < 4; i++) Ws4[t + 256 * i] = W4[t + 256 * i];
    }
    __syncthreads();
    int v = blockIdx.x * 4 + (t >> 6);
    int lane = t & 63;
    float y = layer_body(hin, offsets, csr, nd, bias, Ws, v, lane);
    y = relu_f(y);

    // 16 coalesced 256B fc_w row loads; fc_w streaming overlaps other waves' gathers
    float p[16];
    size_t col = (size_t)v * 64 + lane;
    #pragma unroll
    for (int o = 0; o < 16; o++) p[o] = y * fcw[(size_t)o * NDTOT + col];

    __syncthreads();               // all waves done with Ws -> reuse as scratch
    #pragma unroll
    for (int o = 0; o < 16; o++) Ws[o * 256 + t] = p[o];
    __syncthreads();

    // out_o = sum_t Ws[o*256+t]; thread (o=t>>4, i=t&15) sums t' = m*16+i
    int o = t >> 4, i = t & 15;
    float s = 0.f;
    #pragma unroll
    for (int m = 0; m < 16; m++) s += Ws[o * 256 + m * 16 + i];
    s += __shfl_down(s, 8, 64);
    s += __shfl_down(s, 4, 64);
    s += __shfl_down(s, 2, 64);
    s += __shfl_down(s, 1, 64);
    if (i == 0) partials[blockIdx.x * 16 + o] = s;
}

// ---- fc reduce stage 1: 12500x16 -> 64x16 ----
__global__ __launch_bounds__(256) void k_fc2a(const float* __restrict__ partials, float* __restrict__ part2){
    __shared__ float red[256];
    int t = threadIdx.x; int o = t & 15, rr = t >> 4;
    float s = 0.f;
    for (int r = blockIdx.x * 16 + rr; r < 12500; r += 1024)
        s += partials[r * 16 + o];
    red[t] = s; __syncthreads();
    for (int off = 128; off >= 16; off >>= 1){ if (t < off) red[t] += red[t + off]; __syncthreads(); }
    if (t < 16) part2[blockIdx.x * 16 + t] = red[t];
}

// ---- fc reduce stage 2: 64x16 -> 16 (+bias) ----
__global__ __launch_bounds__(256) void k_fc2b(const float* __restrict__ part2, const float* __restrict__ fcb,
                                              float* __restrict__ out){
    __shared__ float red[256];
    int t = threadIdx.x; int o = t & 15, g = t >> 4;
    float s = 0.f;
    #pragma unroll
    for (int m = 0; m < 4; m++) s += part2[(g + 16 * m) * 16 + o];
    red[t] = s; __syncthreads();
    for (int off = 128; off >= 16; off >>= 1){ if (t < off) red[t] += red[t + off]; __syncthreads(); }
    if (t < 16) out[t] = red[t] + fcb[t];
}

extern "C" void kernel_launch(void* const* d_in, const int* in_sizes, int n_in,
                              void* d_out, int out_size, void* d_ws, size_t ws_size,
                              hipStream_t stream) {
    const float* F     = (const float*)d_in[0];
    const int*   src   = (const int*)d_in[1];
    const int*   dst   = (const int*)d_in[2];
    const float* gcn_w = (const float*)d_in[3];
    const float* gcn_b = (const float*)d_in[4];
    const float* fc_w  = (const float*)d_in[5];
    const float* fc_b  = (const float*)d_in[6];
    float* out = (float*)d_out;

    char* wsp = (char*)d_ws;
    auto alloc = [&](size_t bytes) -> char* {
        char* p = wsp;
        wsp += (bytes + 255) & ~size_t(255);
        return p;
    };
    unsigned* deg      = (unsigned*)alloc(2 * Nn * 4);   // deg_out | deg_in, one memset
    unsigned* deg_out_ = deg;
    unsigned* deg_in_  = deg + Nn;
    unsigned* offsets  = (unsigned*)alloc((Nn + 1) * 4);
    unsigned* cursor   = (unsigned*)alloc(Nn * 4);
    unsigned* bsum     = (unsigned*)alloc(256 * 4);
    unsigned* boff     = (unsigned*)alloc(256 * 4);
    unsigned* csr      = (unsigned*)alloc(Ee * 4);
    float* norm_src    = (float*)alloc(Nn * 4);
    float* norm_dst    = (float*)alloc(Nn * 4);
    float* partials    = (float*)alloc(12500 * 16 * 4);
    float* part2       = (float*)alloc(64 * 16 * 4);
    unsigned short* hA = (unsigned short*)alloc(NDTOT * 2);   // bf16 h ping
    unsigned short* hB = (unsigned short*)alloc(NDTOT * 2);   // bf16 h pong

    hipMemsetAsync(deg, 0, 2 * Nn * 4, stream);

    k_degree<<<Ee / 256, 256, 0, stream>>>(src, dst, deg_out_, deg_in_);
    k_blocksum<<<NBLK, 256, 0, stream>>>(deg_in_, deg_out_, bsum, norm_src, norm_dst);
    k_scanblocks<<<1, 256, 0, stream>>>(bsum, boff, offsets);
    k_offsets<<<NBLK, 256, 0, stream>>>(deg_in_, boff, offsets, cursor);
    k_fillcsr<<<Ee / 256, 256, 0, stream>>>(src, dst, cursor, csr);

    k_h0<<<ND4 / 256, 256, 0, stream>>>(F, norm_src, hA);

    // L0: hA -> hB, L1: hB -> hA (both bf16 prescaled), L2+fc: hA -> partials
    k_layer01<<<Nn / 4, 256, 0, stream>>>(hA, offsets, csr, norm_dst, norm_src,
                                          gcn_w + 0 * 4096, gcn_b + 0 * 64, hB);
    k_layer01<<<Nn / 4, 256, 0, stream>>>(hB, offsets, csr, norm_dst, norm_src,
                                          gcn_w + 1 * 4096, gcn_b + 1 * 64, hA);
    k_layer2fc<<<Nn / 4, 256, 0, stream>>>(hA, offsets, csr, norm_dst,
                                           gcn_w + 2 * 4096, gcn_b + 2 * 64, fc_w, partials);

    k_fc2a<<<64, 256, 0, stream>>>(partials, part2);
    k_fc2b<<<1, 256, 0, stream>>>(part2, fc_b, out);
}

// Round 7
// 540.833 us; speedup vs baseline: 1.0732x; 1.0732x over previous
//
#include <hip/hip_runtime.h>
#include <cstdint>

#define Nn 50000
#define Dd 64
#define Ee 800000
#define NBLK 196          // ceil(Nn/256)
#define FC_BLOCKS 512
#define ND4 (Nn*Dd/4)     // 800000 ushort4/float4 groups (=200000*4... element groups of 4)
#define NDTOT ((size_t)Nn * 64)

__device__ __forceinline__ float relu_f(float v){ return v > 0.f ? v : 0.f; }

// bf16 <-> fp32 (RNE round)
__device__ __forceinline__ unsigned short f2bf(float f){
    unsigned u = __float_as_uint(f);
    u += 0x7fffu + ((u >> 16) & 1u);
    return (unsigned short)(u >> 16);
}
// accumulate 8 packed bf16 (uint4) into fp32[8]
__device__ __forceinline__ void add_bf8(float* a, uint4 u){
    a[0] += __uint_as_float(u.x << 16);
    a[1] += __uint_as_float(u.x & 0xffff0000u);
    a[2] += __uint_as_float(u.y << 16);
    a[3] += __uint_as_float(u.y & 0xffff0000u);
    a[4] += __uint_as_float(u.z << 16);
    a[5] += __uint_as_float(u.z & 0xffff0000u);
    a[6] += __uint_as_float(u.w << 16);
    a[7] += __uint_as_float(u.w & 0xffff0000u);
}
// branch-free row index: clamp e for a safe csr load, select zero-row (Nn) if OOB
__device__ __forceinline__ int rowidx(unsigned e, unsigned end, const unsigned* __restrict__ csr){
    unsigned ec = e < (Ee - 1u) ? e : (Ee - 1u);
    int idx = (int)csr[ec];
    return (e < end) ? idx : Nn;
}

// ---- degree histogram (self-loops added later as +1) ----
__global__ __launch_bounds__(256) void k_degree(const int* __restrict__ src, const int* __restrict__ dst,
                                                unsigned* __restrict__ dout, unsigned* __restrict__ din){
    int e = blockIdx.x * 256 + threadIdx.x;
    if (e < Ee){
        atomicAdd(&dout[src[e]], 1u);
        atomicAdd(&din[dst[e]], 1u);
    }
}

// ---- block sums of deg_in (for scan) + norms fused ----
__global__ __launch_bounds__(256) void k_blocksum(const unsigned* __restrict__ din, const unsigned* __restrict__ dout,
                                                  unsigned* __restrict__ bsum,
                                                  float* __restrict__ ns, float* __restrict__ nd){
    __shared__ unsigned s[256];
    int t = threadIdx.x; int i = blockIdx.x * 256 + t;
    unsigned v = (i < Nn) ? din[i] : 0u;
    s[t] = v;
    if (i < Nn){
        ns[i] = rsqrtf((float)(dout[i] + 1u));   // +1 = self loop
        nd[i] = rsqrtf((float)(v + 1u));
    }
    __syncthreads();
    for (int off = 128; off > 0; off >>= 1){ if (t < off) s[t] += s[t + off]; __syncthreads(); }
    if (t == 0) bsum[blockIdx.x] = s[0];
}

__global__ __launch_bounds__(256) void k_scanblocks(const unsigned* __restrict__ bsum, unsigned* __restrict__ boff,
                                                    unsigned* __restrict__ offsets){
    __shared__ unsigned s[256];
    int t = threadIdx.x;
    unsigned v = (t < NBLK) ? bsum[t] : 0u;
    s[t] = v; __syncthreads();
    for (int off = 1; off < 256; off <<= 1){
        unsigned add = (t >= off) ? s[t - off] : 0u;
        __syncthreads();
        s[t] += add;
        __syncthreads();
    }
    boff[t] = s[t] - v;                       // exclusive prefix of block sums
    if (t == 255) offsets[Nn] = s[255];       // total == Ee
}

__global__ __launch_bounds__(256) void k_offsets(const unsigned* __restrict__ din, const unsigned* __restrict__ boff,
                                                 unsigned* __restrict__ offsets, unsigned* __restrict__ cursor){
    __shared__ unsigned s[256];
    int t = threadIdx.x; int i = blockIdx.x * 256 + t;
    unsigned v = (i < Nn) ? din[i] : 0u;
    s[t] = v; __syncthreads();
    for (int off = 1; off < 256; off <<= 1){
        unsigned add = (t >= off) ? s[t - off] : 0u;
        __syncthreads();
        s[t] += add;
        __syncthreads();
    }
    if (i < Nn){
        unsigned val = s[t] - v + boff[blockIdx.x];
        offsets[i] = val;
        cursor[i]  = val;
    }
}

__global__ __launch_bounds__(256) void k_fillcsr(const int* __restrict__ src, const int* __restrict__ dst,
                                                 unsigned* __restrict__ cursor, unsigned* __restrict__ csr){
    int e = blockIdx.x * 256 + threadIdx.x;
    if (e < Ee){
        unsigned pos = atomicAdd(&cursor[dst[e]], 1u);
        csr[pos] = (unsigned)src[e];
    }
}

// ---- h0 = bf16(F * norm_src); last block zeroes row Nn of BOTH h buffers ----
__global__ __launch_bounds__(256) void k_h0(const float* __restrict__ x, const float* __restrict__ ns,
                                            unsigned short* __restrict__ hA, unsigned short* __restrict__ hB){
    int i = blockIdx.x * 256 + threadIdx.x;
    if (i < ND4){
        const float4* x4 = (const float4*)x;
        float s = ns[i >> 4];
        float4 v = x4[i];
        ushort4 o;
        o.x = f2bf(v.x * s); o.y = f2bf(v.y * s);
        o.z = f2bf(v.z * s); o.w = f2bf(v.w * s);
        ((ushort4*)hA)[i] = o;
    } else {
        int j = i - ND4;                 // zero row at node index Nn (16 ushort4 per row)
        if (j < 16){
            ushort4 z = make_ushort4(0, 0, 0, 0);
            ((ushort4*)hA)[ND4 + j] = z;
            ((ushort4*)hB)[ND4 + j] = z;
        }
    }
}

// ---- SpMM gather over bf16 h: one wave per node; branch-free 32-edge burst.
// slot = lane>>3 (8 edge slots), sub = lane&7 (16B chunk). 4 segments' csr
// loads issue in parallel (OOB -> zero row Nn), then 4 row loads in parallel:
// two dependency levels for 99.99% of nodes (Poisson(16), P[deg>32]~3e-5). ----
__global__ __launch_bounds__(256) void k_gather(const unsigned short* __restrict__ h,
                                                const unsigned* __restrict__ offsets,
                                                const unsigned* __restrict__ csr, const float* __restrict__ nd,
                                                float* __restrict__ agg){
    int v = blockIdx.x * 4 + (threadIdx.x >> 6);   // 12500 blocks * 4 waves
    int lane = threadIdx.x & 63;
    int slot = lane >> 3;
    int sub  = lane & 7;
    const uint4* h16 = (const uint4*)h;   // 8 uint4 per 128B row

    unsigned beg = offsets[v], end = offsets[v + 1];
    unsigned e0 = beg + slot;

    // all 4 csr loads independent (clamped), then 4 row loads independent
    int i0 = rowidx(e0,      end, csr);
    int i1 = rowidx(e0 + 8,  end, csr);
    int i2 = rowidx(e0 + 16, end, csr);
    int i3 = rowidx(e0 + 24, end, csr);
    uint4 u0 = h16[(size_t)i0 * 8 + sub];
    uint4 u1 = h16[(size_t)i1 * 8 + sub];
    uint4 u2 = h16[(size_t)i2 * 8 + sub];
    uint4 u3 = h16[(size_t)i3 * 8 + sub];

    float acc[8];
    #pragma unroll
    for (int i = 0; i < 8; i++) acc[i] = 0.f;
    if (slot == 0) add_bf8(acc, h16[(size_t)v * 8 + sub]);   // self loop
    add_bf8(acc, u0);
    add_bf8(acc, u1);
    add_bf8(acc, u2);
    add_bf8(acc, u3);

    // rare tail: degree > 32 (a handful of nodes in the whole graph)
    for (unsigned e = e0 + 32; e < end; e += 8){
        add_bf8(acc, h16[(size_t)((int)csr[e]) * 8 + sub]);
    }

    // reduce over slots (lane bits 3..5)
    #pragma unroll
    for (int i = 0; i < 8; i++) acc[i] += __shfl_xor(acc[i], 8, 64);
    #pragma unroll
    for (int i = 0; i < 8; i++) acc[i] += __shfl_xor(acc[i], 16, 64);
    #pragma unroll
    for (int i = 0; i < 8; i++) acc[i] += __shfl_xor(acc[i], 32, 64);

    if (slot == 0){
        float s = nd[v];
        float4* aggp = (float4*)agg;
        aggp[(size_t)v * 16 + sub * 2 + 0] = make_float4(acc[0] * s, acc[1] * s, acc[2] * s, acc[3] * s);
        aggp[(size_t)v * 16 + sub * 2 + 1] = make_float4(acc[4] * s, acc[5] * s, acc[6] * s, acc[7] * s);
    }
}

// ---- y = relu(agg @ W + b); out either bf16(y*ns) (layers 0,1) or fp32 y (layer 2) ----
__global__ __launch_bounds__(256) void k_gemm(const float* __restrict__ agg, const float* __restrict__ W,
                                              const float* __restrict__ bias, const float* __restrict__ ns,
                                              void* __restrict__ xout, int bf16_prescale_out){
    __shared__ float As[64 * 65];   // pad 65 -> conflict-free column reads
    __shared__ float Ws[64 * 64];   // W[k][n]
    int t = threadIdx.x;
    int m_base = blockIdx.x * 64;
    const float4* W4   = (const float4*)W;
    float4* Ws4        = (float4*)Ws;
    const float4* agg4 = (const float4*)agg;
    #pragma unroll
    for (int i = 0; i < 4; i++){
        int g = t + 256 * i;              // 1024 float4s
        Ws4[g] = W4[g];
        int m = g >> 4, q = g & 15;
        int node = m_base + m;
        float4 v = make_float4(0.f, 0.f, 0.f, 0.f);
        if (node < Nn) v = agg4[node * 16 + q];
        float* dp = &As[m * 65 + q * 4];
        dp[0] = v.x; dp[1] = v.y; dp[2] = v.z; dp[3] = v.w;
    }
    __syncthreads();
    int tm = t >> 4, tn = t & 15;
    float acc[4][4];
    #pragma unroll
    for (int i = 0; i < 4; i++)
        #pragma unroll
        for (int j = 0; j < 4; j++) acc[i][j] = 0.f;
    #pragma unroll 4
    for (int k = 0; k < 64; k++){
        float4 w = *(const float4*)&Ws[k * 64 + tn * 4];
        float a[4];
        #pragma unroll
        for (int i = 0; i < 4; i++) a[i] = As[(tm * 4 + i) * 65 + k];
        #pragma unroll
        for (int i = 0; i < 4; i++){
            acc[i][0] += a[i] * w.x;
            acc[i][1] += a[i] * w.y;
            acc[i][2] += a[i] * w.z;
            acc[i][3] += a[i] * w.w;
        }
    }
    float4 b4 = ((const float4*)bias)[tn];
    #pragma unroll
    for (int i = 0; i < 4; i++){
        int node = m_base + tm * 4 + i;
        if (node < Nn){
            float4 r;
            r.x = relu_f(acc[i][0] + b4.x);
            r.y = relu_f(acc[i][1] + b4.y);
            r.z = relu_f(acc[i][2] + b4.z);
            r.w = relu_f(acc[i][3] + b4.w);
            if (bf16_prescale_out){
                float s = ns[node];   // relu(x)*ns == prescaled h for next layer (ns>0)
                ushort4 o;
                o.x = f2bf(r.x * s); o.y = f2bf(r.y * s);
                o.z = f2bf(r.z * s); o.w = f2bf(r.w * s);
                ((ushort4*)xout)[node * 16 + tn] = o;
            } else {
                ((float4*)xout)[node * 16 + tn] = r;
            }
        }
    }
}

// ---- fc: out[o] = fc_b[o] + sum_i fc_w[o][i]*x[i], 16 partials per thread ----
__global__ __launch_bounds__(256) void k_fc(const float* __restrict__ fcw, const float* __restrict__ x,
                                            float* __restrict__ partials){
    int t = threadIdx.x;
    const float4* x4 = (const float4*)x;
    const float4* w4 = (const float4*)fcw;
    float p[16];
    #pragma unroll
    for (int o = 0; o < 16; o++) p[o] = 0.f;
    for (int i = blockIdx.x * 256 + t; i < ND4; i += FC_BLOCKS * 256){
        float4 xv = x4[i];
        #pragma unroll
        for (int o = 0; o < 16; o++){
            float4 wv = w4[(size_t)o * ND4 + i];
            p[o] += wv.x * xv.x + wv.y * xv.y + wv.z * xv.z + wv.w * xv.w;
        }
    }
    #pragma unroll
    for (int o = 0; o < 16; o++){
        for (int off = 32; off > 0; off >>= 1) p[o] += __shfl_down(p[o], off, 64);
    }
    __shared__ float red[4][16];
    int lane = t & 63, wid = t >> 6;
    if (lane == 0){
        #pragma unroll
        for (int o = 0; o < 16; o++) red[wid][o] = p[o];
    }
    __syncthreads();
    if (t < 16) partials[blockIdx.x * 16 + t] = red[0][t] + red[1][t] + red[2][t] + red[3][t];
}

__global__ __launch_bounds__(256) void k_fc2(const float* __restrict__ partials, const float* __restrict__ fcb,
                                             float* __restrict__ out){
    __shared__ float red[256];
    int t = threadIdx.x; int o = t & 15, j0 = t >> 4;
    float s = 0.f;
    for (int j = j0; j < FC_BLOCKS; j += 16) s += partials[j * 16 + o];
    red[t] = s; __syncthreads();
    for (int off = 128; off >= 16; off >>= 1){ if (t < off) red[t] += red[t + off]; __syncthreads(); }
    if (t < 16) out[t] = red[t] + fcb[t];
}

extern "C" void kernel_launch(void* const* d_in, const int* in_sizes, int n_in,
                              void* d_out, int out_size, void* d_ws, size_t ws_size,
                              hipStream_t stream) {
    const float* F     = (const float*)d_in[0];
    const int*   src   = (const int*)d_in[1];
    const int*   dst   = (const int*)d_in[2];
    const float* gcn_w = (const float*)d_in[3];
    const float* gcn_b = (const float*)d_in[4];
    const float* fc_w  = (const float*)d_in[5];
    const float* fc_b  = (const float*)d_in[6];
    float* out = (float*)d_out;

    char* wsp = (char*)d_ws;
    auto alloc = [&](size_t bytes) -> char* {
        char* p = wsp;
        wsp += (bytes + 255) & ~size_t(255);
        return p;
    };
    unsigned* deg      = (unsigned*)alloc(2 * Nn * 4);   // deg_out | deg_in, one memset
    unsigned* deg_out_ = deg;
    unsigned* deg_in_  = deg + Nn;
    unsigned* offsets  = (unsigned*)alloc((Nn + 1) * 4);
    unsigned* cursor   = (unsigned*)alloc(Nn * 4);
    unsigned* bsum     = (unsigned*)alloc(256 * 4);
    unsigned* boff     = (unsigned*)alloc(256 * 4);
    unsigned* csr      = (unsigned*)alloc(Ee * 4);
    float* norm_src    = (float*)alloc(Nn * 4);
    float* norm_dst    = (float*)alloc(Nn * 4);
    float* partials    = (float*)alloc(FC_BLOCKS * 16 * 4);
    unsigned short* hA = (unsigned short*)alloc((NDTOT + 64) * 2);   // bf16 h ping (+zero row)
    unsigned short* hB = (unsigned short*)alloc((NDTOT + 64) * 2);   // bf16 h pong (+zero row)
    float* aggb        = (float*)alloc(NDTOT * 4);
    float* xf          = (float*)alloc(NDTOT * 4);                   // final fp32 x for fc

    hipMemsetAsync(deg, 0, 2 * Nn * 4, stream);

    k_degree<<<Ee / 256, 256, 0, stream>>>(src, dst, deg_out_, deg_in_);
    k_blocksum<<<NBLK, 256, 0, stream>>>(deg_in_, deg_out_, bsum, norm_src, norm_dst);
    k_scanblocks<<<1, 256, 0, stream>>>(bsum, boff, offsets);
    k_offsets<<<NBLK, 256, 0, stream>>>(deg_in_, boff, offsets, cursor);
    k_fillcsr<<<Ee / 256, 256, 0, stream>>>(src, dst, cursor, csr);

    k_h0<<<ND4 / 256 + 1, 256, 0, stream>>>(F, norm_src, hA, hB);

    int nblk_gemm = (Nn + 63) / 64;
    // L0: hA -> agg -> hB (bf16 prescaled)
    k_gather<<<Nn / 4, 256, 0, stream>>>(hA, offsets, csr, norm_dst, aggb);
    k_gemm<<<nblk_gemm, 256, 0, stream>>>(aggb, gcn_w + 0 * 4096, gcn_b + 0 * 64, norm_src, hB, 1);
    // L1: hB -> agg -> hA (bf16 prescaled)
    k_gather<<<Nn / 4, 256, 0, stream>>>(hB, offsets, csr, norm_dst, aggb);
    k_gemm<<<nblk_gemm, 256, 0, stream>>>(aggb, gcn_w + 1 * 4096, gcn_b + 1 * 64, norm_src, hA, 1);
    // L2: hA -> agg -> xf (fp32 plain)
    k_gather<<<Nn / 4, 256, 0, stream>>>(hA, offsets, csr, norm_dst, aggb);
    k_gemm<<<nblk_gemm, 256, 0, stream>>>(aggb, gcn_w + 2 * 4096, gcn_b + 2 * 64, norm_src, xf, 0);

    k_fc<<<FC_BLOCKS, 256, 0, stream>>>(fc_w, xf, partials);
    k_fc2<<<1, 256, 0, stream>>>(partials, fc_b, out);
}